// Round 7
// baseline (691.811 us; speedup 1.0000x reference)
//
#include <hip/hip_runtime.h>
#include <hip/hip_bf16.h>

typedef __bf16 bf16;
typedef __attribute__((ext_vector_type(8))) __bf16 bf16x8;
typedef __attribute__((ext_vector_type(4))) float f32x4;

#define S_LEN  4096
#define HIDDEN 2048
#define N_HEADS 8
#define D_HEAD 256
#define QKV_N  2560   // 2048 q | 256 k | 256 v
#define NEG_BIG (-1e30f)

// ws layout (bytes)
#define OFF_WQKVT 0u
#define OFF_WOT   10485760u
#define OFF_QKV   18874368u
#define OFF_VT    39845888u
#define OFF_AOUT  41943040u
#define OFF_FLAG  58720256u
#define WS_NEED   58720320u

// ------------------------------------------------------------------
// dtype detect (inputs are fp32; round-6 confirmed flag fires)
// ------------------------------------------------------------------
__global__ __launch_bounds__(256) void detect_dtype(const unsigned short* __restrict__ w,
                                                    int* __restrict__ flag) {
  __shared__ int bad;
  if (threadIdx.x == 0) bad = 0;
  __syncthreads();
  int local = 0;
  for (int i = threadIdx.x; i < 4096; i += 256) {
    int e = (w[i] >> 7) & 0xFF;
    if (e >= 130) local = 1;
  }
  if (local) atomicOr(&bad, 1);
  __syncthreads();
  if (threadIdx.x == 0) *flag = bad;
}

__device__ __forceinline__ bf16x8 load8(const void* p, size_t idx, bool f32) {
  if (f32) {
    const float* q = (const float*)p + idx;
    bf16x8 r;
#pragma unroll
    for (int j = 0; j < 8; ++j) r[j] = (bf16)q[j];
    return r;
  }
  return *(const bf16x8*)((const bf16*)p + idx);
}

// ------------------------------------------------------------------
// 64x64 LDS-tiled transpose: dst[c][r] = src[r][c]  (src may be fp32)
// ------------------------------------------------------------------
__device__ __forceinline__ void transpose_tile64(const void* __restrict__ src, size_t sbase,
                                                 int sld, bool f32,
                                                 bf16* __restrict__ dst, int dld,
                                                 bf16 (*T)[72]) {
  int tid = threadIdx.x;
  int r  = tid >> 2;
  int c4 = (tid & 3) * 16;
  *(bf16x8*)(&T[r][c4])     = load8(src, sbase + (size_t)r * sld + c4, f32);
  *(bf16x8*)(&T[r][c4 + 8]) = load8(src, sbase + (size_t)r * sld + c4 + 8, f32);
  __syncthreads();
  bf16x8 v0, v1;
#pragma unroll
  for (int j = 0; j < 8; ++j) { v0[j] = T[c4 + j][r]; v1[j] = T[c4 + 8 + j][r]; }
  *(bf16x8*)(dst + (size_t)r * dld + c4)     = v0;
  *(bf16x8*)(dst + (size_t)r * dld + c4 + 8) = v1;
}

__global__ __launch_bounds__(256) void build_wqkvT(const void* __restrict__ wq,
                                                   const void* __restrict__ wk,
                                                   const void* __restrict__ wv,
                                                   bf16* __restrict__ dst,
                                                   const int* __restrict__ flag) {
  __shared__ __align__(16) bf16 T[64][72];
  bool f32 = (*flag != 0);
  int n0 = blockIdx.x * 64;
  int k0 = blockIdx.y * 64;
  const void* src; int ld, c0;
  if (n0 < 2048)      { src = wq; ld = 2048; c0 = n0; }
  else if (n0 < 2304) { src = wk; ld = 256;  c0 = n0 - 2048; }
  else                { src = wv; ld = 256;  c0 = n0 - 2304; }
  transpose_tile64(src, (size_t)k0 * ld + c0, ld, f32,
                   dst + (size_t)n0 * HIDDEN + k0, HIDDEN, T);
}

__global__ __launch_bounds__(256) void transpose_any(const void* __restrict__ src, int sbase,
                                                     int sld,
                                                     bf16* __restrict__ dst, int dld,
                                                     const int* __restrict__ flag) {
  __shared__ __align__(16) bf16 T[64][72];
  bool f32 = flag && (*flag != 0);
  int c0 = blockIdx.x * 64;
  int r0 = blockIdx.y * 64;
  transpose_tile64(src, (size_t)sbase + (size_t)r0 * sld + c0, sld, f32,
                   dst + (size_t)c0 * dld + r0, dld, T);
}

// ------------------------------------------------------------------
// GEMM (unchanged from round 6): 128x128 tile, BK=32, VGPR staging.
// ------------------------------------------------------------------
__global__ __launch_bounds__(256) void gemm128(const void* __restrict__ A,
                                               const bf16* __restrict__ BT,
                                               void* __restrict__ C,
                                               int M, int N, int K,
                                               const int* __restrict__ aflag,
                                               const int* __restrict__ cflag) {
  __shared__ __align__(16) bf16 As[128][40];
  __shared__ __align__(16) bf16 Bs[128][40];
  bool af32 = aflag && (*aflag != 0);
  bool cf32 = cflag && (*cflag != 0);
  int tid  = threadIdx.x;
  int w = tid >> 6, lane = tid & 63;
  int quad = lane >> 4, l16 = lane & 15;
  int bm = blockIdx.y * 128, bn = blockIdx.x * 128;
  int wm = (w >> 1) * 64, wn = (w & 1) * 64;

  int sr = tid >> 2, sc = (tid & 3) * 8;
  size_t abase = (size_t)(bm + sr) * K + sc;
  const bf16* Bg = BT + (size_t)(bn + sr) * K + sc;

  f32x4 acc[4][4] = {};
  for (int kt = 0; kt < K; kt += 32) {
    bf16x8 a0 = load8(A, abase + kt, af32);
    bf16x8 a1 = load8(A, abase + kt + (size_t)64 * K, af32);
    bf16x8 b0 = *(const bf16x8*)(Bg + kt);
    bf16x8 b1 = *(const bf16x8*)(Bg + kt + (size_t)64 * K);
    __syncthreads();
    *(bf16x8*)(&As[sr][sc])      = a0;
    *(bf16x8*)(&As[sr + 64][sc]) = a1;
    *(bf16x8*)(&Bs[sr][sc])      = b0;
    *(bf16x8*)(&Bs[sr + 64][sc]) = b1;
    __syncthreads();
    bf16x8 af[4], bfr[4];
#pragma unroll
    for (int mt = 0; mt < 4; ++mt)
      af[mt] = *(const bf16x8*)(&As[wm + mt * 16 + l16][quad * 8]);
#pragma unroll
    for (int nt = 0; nt < 4; ++nt)
      bfr[nt] = *(const bf16x8*)(&Bs[wn + nt * 16 + l16][quad * 8]);
#pragma unroll
    for (int mt = 0; mt < 4; ++mt)
#pragma unroll
      for (int nt = 0; nt < 4; ++nt)
        acc[mt][nt] = __builtin_amdgcn_mfma_f32_16x16x32_bf16(af[mt], bfr[nt],
                                                              acc[mt][nt], 0, 0, 0);
  }
#pragma unroll
  for (int mt = 0; mt < 4; ++mt)
#pragma unroll
    for (int nt = 0; nt < 4; ++nt)
#pragma unroll
      for (int r = 0; r < 4; ++r) {
        int row = bm + wm + mt * 16 + quad * 4 + r;
        int col = bn + wn + nt * 16 + l16;
        size_t off = (size_t)row * N + col;
        float v = acc[mt][nt][r];
        if (cf32) ((float*)C)[off] = v;
        else      ((bf16*)C)[off] = (bf16)v;
      }
}

// ------------------------------------------------------------------
// RoPE (unchanged)
// ------------------------------------------------------------------
__global__ __launch_bounds__(256) void rope_kernel(bf16* __restrict__ qkv,
                                                   const int* __restrict__ pos) {
  int s = blockIdx.x;
  float p = (float)pos[s];
  bf16* row = qkv + (size_t)s * QKV_N;
  for (int i = threadIdx.x; i < 9 * 128; i += 256) {
    int h = i >> 7, d = i & 127;
    float inv = __expf(-(float)d * (9.210340371976184f / 128.0f));
    float th = p * inv;
    float sn, c;
    sincosf(th, &sn, &c);
    c  = (float)(bf16)c;
    sn = (float)(bf16)sn;
    bf16* x = row + ((h < 8) ? h * 256 : 2048);
    float x1 = (float)x[d], x2 = (float)x[d + 128];
    x[d]       = (bf16)(x1 * c - x2 * sn);
    x[d + 128] = (bf16)(x2 * c + x1 * sn);
  }
}

// ------------------------------------------------------------------
// Flash attention v3. Block = (head, 64 q rows), 2 waves x 32 q-rows
// (each wave: 2 m-tiles sharing every K/V fragment -> halves LDS reads).
// kv-tile = 32; separate K/V LDS buffers -> 2 barriers/iter.
// Grid 512 longest-first, 37 KB LDS -> 2 blocks/CU co-resident.
// ------------------------------------------------------------------
__global__ __launch_bounds__(128) void attn_kernel(const bf16* __restrict__ qkv,
                                                   const bf16* __restrict__ VT,
                                                   bf16* __restrict__ aout) {
  __shared__ __align__(16) bf16 Ks[32 * 256];   // [kv32][d256], 8-chunk XOR swizzle
  __shared__ __align__(16) bf16 Vs[256 * 32];   // [d256][kv32], 4-chunk XOR swizzle
  __shared__ __align__(16) bf16 Pl[2][32][40];  // per-wave P: C-layout -> A-layout
  int tid  = threadIdx.x;
  int w = tid >> 6, lane = tid & 63;
  int quad = lane >> 4, l16 = lane & 15;
  int bx   = blockIdx.x;
  int head = bx & 7;
  int B    = 63 - (bx >> 3);        // longest q-blocks dispatched first
  int qb   = B * 64;
  int qw   = qb + w * 32;           // this wave's 32 q rows

  // Q fragments (A-layout), 2 m-tiles, pre-scaled by 1/sqrt(256)
  bf16x8 qf[2][8];
#pragma unroll
  for (int m = 0; m < 2; ++m) {
    const bf16* qrow = qkv + (size_t)(qw + m * 16 + l16) * QKV_N + head * D_HEAD + quad * 8;
#pragma unroll
    for (int dc = 0; dc < 8; ++dc) {
      bf16x8 t = *(const bf16x8*)(qrow + dc * 32);
#pragma unroll
      for (int j = 0; j < 8; ++j) t[j] = (bf16)((float)t[j] * 0.0625f);
      qf[m][dc] = t;
    }
  }

  f32x4 o[2][16] = {};
  float mrow[2][4], lrow[2][4];
#pragma unroll
  for (int m = 0; m < 2; ++m)
#pragma unroll
    for (int r = 0; r < 4; ++r) { mrow[m][r] = NEG_BIG; lrow[m][r] = 0.f; }

  int kro = tid >> 5, kcc = tid & 31;   // K staging: rows c*4+kro, chunk kcc
  int vro = tid >> 2, vcc = tid & 3;    // V staging: rows c*32+vro, chunk vcc

  int ntiles = 2 * B + 2;
  for (int kt = 0; kt < ntiles; ++kt) {
    int kv0 = kt << 5;
    __syncthreads();                       // prior iter's K/V reads done
    // ---- stage K tile [32 kv][256 d] ----
#pragma unroll
    for (int c = 0; c < 8; ++c) {
      int r = c * 4 + kro;
      bf16x8 t = *(const bf16x8*)(qkv + (size_t)(kv0 + r) * QKV_N + 2048 + kcc * 8);
      *(bf16x8*)(Ks + r * 256 + ((kcc ^ r) * 8)) = t;
    }
    // ---- stage V^T tile [256 d][32 kv] ----
#pragma unroll
    for (int c = 0; c < 8; ++c) {
      int r = c * 32 + vro;
      bf16x8 t = *(const bf16x8*)(VT + (size_t)r * S_LEN + kv0 + vcc * 8);
      *(bf16x8*)(Vs + r * 32 + ((vcc ^ (r & 3)) * 8)) = t;
    }
    __syncthreads();
    // ---- S = Q K^T : 2 m-tiles x 2 kv n-tiles x 8 d chunks ----
    f32x4 sv[2][2] = {};
#pragma unroll
    for (int dc = 0; dc < 8; ++dc)
#pragma unroll
      for (int n = 0; n < 2; ++n) {
        int row = n * 16 + l16;
        bf16x8 kf = *(const bf16x8*)(Ks + row * 256 + (((dc << 2) + quad) ^ row) * 8);
#pragma unroll
        for (int m = 0; m < 2; ++m)
          sv[m][n] = __builtin_amdgcn_mfma_f32_16x16x32_bf16(qf[m][dc], kf, sv[m][n], 0, 0, 0);
      }
    // ---- online softmax per m-tile (16x32 each) ----
#pragma unroll
    for (int m = 0; m < 2; ++m) {
      int qwm = qw + m * 16;
      bool needmask = (kv0 + 31 > qwm);
      float p[2][4], mt[4];
#pragma unroll
      for (int r = 0; r < 4; ++r) mt[r] = NEG_BIG;
#pragma unroll
      for (int n = 0; n < 2; ++n)
#pragma unroll
        for (int r = 0; r < 4; ++r) {
          float x = sv[m][n][r];
          if (needmask && (kv0 + n * 16 + l16 > qwm + quad * 4 + r)) x = NEG_BIG;
          p[n][r] = x;
          mt[r] = fmaxf(mt[r], x);
        }
#pragma unroll
      for (int off = 8; off >= 1; off >>= 1)
#pragma unroll
        for (int r = 0; r < 4; ++r)
          mt[r] = fmaxf(mt[r], __shfl_xor(mt[r], off, 16));
      float alpha[4], rs[4];
#pragma unroll
      for (int r = 0; r < 4; ++r) {
        float mnew = fmaxf(mrow[m][r], mt[r]);
        alpha[r] = __expf(mrow[m][r] - mnew);
        mrow[m][r] = mnew;
        rs[r] = 0.f;
      }
#pragma unroll
      for (int n = 0; n < 2; ++n)
#pragma unroll
        for (int r = 0; r < 4; ++r) {
          p[n][r] = __expf(p[n][r] - mrow[m][r]);
          rs[r] += p[n][r];
        }
#pragma unroll
      for (int off = 8; off >= 1; off >>= 1)
#pragma unroll
        for (int r = 0; r < 4; ++r)
          rs[r] += __shfl_xor(rs[r], off, 16);
#pragma unroll
      for (int r = 0; r < 4; ++r) lrow[m][r] = lrow[m][r] * alpha[r] + rs[r];
#pragma unroll
      for (int dt = 0; dt < 16; ++dt)
#pragma unroll
        for (int r = 0; r < 4; ++r) o[m][dt][r] *= alpha[r];
      // P (C/D layout) -> per-wave LDS (A layout target)
#pragma unroll
      for (int n = 0; n < 2; ++n)
#pragma unroll
        for (int r = 0; r < 4; ++r)
          Pl[w][m * 16 + quad * 4 + r][n * 16 + l16] = (bf16)p[n][r];
    }
    asm volatile("s_waitcnt lgkmcnt(0)" ::: "memory");  // wave-local Pl ordering
    // ---- O += P @ V ----
    bf16x8 pa[2];
#pragma unroll
    for (int m = 0; m < 2; ++m)
      pa[m] = *(const bf16x8*)(&Pl[w][m * 16 + l16][quad * 8]);
#pragma unroll
    for (int dt = 0; dt < 16; ++dt) {
      int row = dt * 16 + l16;
      bf16x8 vf = *(const bf16x8*)(Vs + row * 32 + ((quad ^ (row & 3)) * 8));
#pragma unroll
      for (int m = 0; m < 2; ++m)
        o[m][dt] = __builtin_amdgcn_mfma_f32_16x16x32_bf16(pa[m], vf, o[m][dt], 0, 0, 0);
    }
  }
  // ---- epilogue ----
#pragma unroll
  for (int m = 0; m < 2; ++m) {
    float invl[4];
#pragma unroll
    for (int r = 0; r < 4; ++r) invl[r] = 1.0f / lrow[m][r];
    bf16* orow = aout + (size_t)(qw + m * 16 + quad * 4) * HIDDEN + head * D_HEAD + l16;
#pragma unroll
    for (int dt = 0; dt < 16; ++dt)
#pragma unroll
      for (int r = 0; r < 4; ++r)
        orow[(size_t)r * HIDDEN + dt * 16] = (bf16)(o[m][dt][r] * invl[r]);
  }
}

// ------------------------------------------------------------------
extern "C" void kernel_launch(void* const* d_in, const int* in_sizes, int n_in,
                              void* d_out, int out_size, void* d_ws, size_t ws_size,
                              hipStream_t stream) {
  if (ws_size < (size_t)WS_NEED) return;
  const void* hs  = d_in[0];
  const int*  pos = (const int*)d_in[1];
  const void* wq  = d_in[2];
  const void* wk  = d_in[3];
  const void* wv  = d_in[4];
  const void* wo  = d_in[5];

  char* ws = (char*)d_ws;
  bf16* wqkvT = (bf16*)(ws + OFF_WQKVT);   // [2560][2048]
  bf16* woT   = (bf16*)(ws + OFF_WOT);     // [2048][2048]
  bf16* qkv   = (bf16*)(ws + OFF_QKV);     // [4096][2560]
  bf16* VT    = (bf16*)(ws + OFF_VT);      // [256][4096]
  bf16* aout  = (bf16*)(ws + OFF_AOUT);    // [4096][2048]
  int*  flag  = (int*)(ws + OFF_FLAG);

  detect_dtype<<<1, 256, 0, stream>>>((const unsigned short*)wq, flag);
  build_wqkvT<<<dim3(QKV_N / 64, HIDDEN / 64), 256, 0, stream>>>(wq, wk, wv, wqkvT, flag);
  transpose_any<<<dim3(HIDDEN / 64, HIDDEN / 64), 256, 0, stream>>>(wo, 0, HIDDEN,
                                                                    woT, HIDDEN, flag);
  gemm128<<<dim3(QKV_N / 128, S_LEN / 128), 256, 0, stream>>>(hs, wqkvT, qkv,
                                                              S_LEN, QKV_N, HIDDEN,
                                                              flag, nullptr);
  rope_kernel<<<S_LEN, 256, 0, stream>>>(qkv, pos);
  transpose_any<<<dim3(D_HEAD / 64, S_LEN / 64), 256, 0, stream>>>(qkv, 2304, QKV_N,
                                                                   VT, S_LEN, nullptr);
  attn_kernel<<<N_HEADS * 64, 128, 0, stream>>>(qkv, VT, aout);
  gemm128<<<dim3(HIDDEN / 128, S_LEN / 128), 256, 0, stream>>>(aout, woT, d_out,
                                                               S_LEN, HIDDEN, HIDDEN,
                                                               nullptr, flag);
}

// Round 8
// 638.225 us; speedup vs baseline: 1.0840x; 1.0840x over previous
//
#include <hip/hip_runtime.h>
#include <hip/hip_bf16.h>

typedef __bf16 bf16;
typedef __attribute__((ext_vector_type(8))) __bf16 bf16x8;
typedef __attribute__((ext_vector_type(4))) float f32x4;

#define S_LEN  4096
#define HIDDEN 2048
#define N_HEADS 8
#define D_HEAD 256
#define QKV_N  2560   // 2048 q | 256 k | 256 v
#define NEG_BIG (-1e30f)

// ws layout (bytes)
#define OFF_WQKVT 0u
#define OFF_WOT   10485760u
#define OFF_QKV   18874368u
#define OFF_VT    39845888u
#define OFF_AOUT  41943040u
#define OFF_FLAG  58720256u
#define WS_NEED   58720320u

// ------------------------------------------------------------------
// dtype detect (inputs are fp32; round-6 confirmed flag fires)
// ------------------------------------------------------------------
__global__ __launch_bounds__(256) void detect_dtype(const unsigned short* __restrict__ w,
                                                    int* __restrict__ flag) {
  __shared__ int bad;
  if (threadIdx.x == 0) bad = 0;
  __syncthreads();
  int local = 0;
  for (int i = threadIdx.x; i < 4096; i += 256) {
    int e = (w[i] >> 7) & 0xFF;
    if (e >= 130) local = 1;
  }
  if (local) atomicOr(&bad, 1);
  __syncthreads();
  if (threadIdx.x == 0) *flag = bad;
}

__device__ __forceinline__ bf16x8 load8(const void* p, size_t idx, bool f32) {
  if (f32) {
    const float* q = (const float*)p + idx;
    bf16x8 r;
#pragma unroll
    for (int j = 0; j < 8; ++j) r[j] = (bf16)q[j];
    return r;
  }
  return *(const bf16x8*)((const bf16*)p + idx);
}

// ------------------------------------------------------------------
// 64x64 LDS-tiled transpose: dst[c][r] = src[r][c]  (src may be fp32)
// ------------------------------------------------------------------
__device__ __forceinline__ void transpose_tile64(const void* __restrict__ src, size_t sbase,
                                                 int sld, bool f32,
                                                 bf16* __restrict__ dst, int dld,
                                                 bf16 (*T)[72]) {
  int tid = threadIdx.x;
  int r  = tid >> 2;
  int c4 = (tid & 3) * 16;
  *(bf16x8*)(&T[r][c4])     = load8(src, sbase + (size_t)r * sld + c4, f32);
  *(bf16x8*)(&T[r][c4 + 8]) = load8(src, sbase + (size_t)r * sld + c4 + 8, f32);
  __syncthreads();
  bf16x8 v0, v1;
#pragma unroll
  for (int j = 0; j < 8; ++j) { v0[j] = T[c4 + j][r]; v1[j] = T[c4 + 8 + j][r]; }
  *(bf16x8*)(dst + (size_t)r * dld + c4)     = v0;
  *(bf16x8*)(dst + (size_t)r * dld + c4 + 8) = v1;
}

__global__ __launch_bounds__(256) void build_wqkvT(const void* __restrict__ wq,
                                                   const void* __restrict__ wk,
                                                   const void* __restrict__ wv,
                                                   bf16* __restrict__ dst,
                                                   const int* __restrict__ flag) {
  __shared__ __align__(16) bf16 T[64][72];
  bool f32 = (*flag != 0);
  int n0 = blockIdx.x * 64;
  int k0 = blockIdx.y * 64;
  const void* src; int ld, c0;
  if (n0 < 2048)      { src = wq; ld = 2048; c0 = n0; }
  else if (n0 < 2304) { src = wk; ld = 256;  c0 = n0 - 2048; }
  else                { src = wv; ld = 256;  c0 = n0 - 2304; }
  transpose_tile64(src, (size_t)k0 * ld + c0, ld, f32,
                   dst + (size_t)n0 * HIDDEN + k0, HIDDEN, T);
}

__global__ __launch_bounds__(256) void transpose_any(const void* __restrict__ src, int sbase,
                                                     int sld,
                                                     bf16* __restrict__ dst, int dld,
                                                     const int* __restrict__ flag) {
  __shared__ __align__(16) bf16 T[64][72];
  bool f32 = flag && (*flag != 0);
  int c0 = blockIdx.x * 64;
  int r0 = blockIdx.y * 64;
  transpose_tile64(src, (size_t)sbase + (size_t)r0 * sld + c0, sld, f32,
                   dst + (size_t)c0 * dld + r0, dld, T);
}

// ------------------------------------------------------------------
// GEMM (unchanged): 128x128 tile, BK=32, VGPR staging.
// ------------------------------------------------------------------
__global__ __launch_bounds__(256) void gemm128(const void* __restrict__ A,
                                               const bf16* __restrict__ BT,
                                               void* __restrict__ C,
                                               int M, int N, int K,
                                               const int* __restrict__ aflag,
                                               const int* __restrict__ cflag) {
  __shared__ __align__(16) bf16 As[128][40];
  __shared__ __align__(16) bf16 Bs[128][40];
  bool af32 = aflag && (*aflag != 0);
  bool cf32 = cflag && (*cflag != 0);
  int tid  = threadIdx.x;
  int w = tid >> 6, lane = tid & 63;
  int quad = lane >> 4, l16 = lane & 15;
  int bm = blockIdx.y * 128, bn = blockIdx.x * 128;
  int wm = (w >> 1) * 64, wn = (w & 1) * 64;

  int sr = tid >> 2, sc = (tid & 3) * 8;
  size_t abase = (size_t)(bm + sr) * K + sc;
  const bf16* Bg = BT + (size_t)(bn + sr) * K + sc;

  f32x4 acc[4][4] = {};
  for (int kt = 0; kt < K; kt += 32) {
    bf16x8 a0 = load8(A, abase + kt, af32);
    bf16x8 a1 = load8(A, abase + kt + (size_t)64 * K, af32);
    bf16x8 b0 = *(const bf16x8*)(Bg + kt);
    bf16x8 b1 = *(const bf16x8*)(Bg + kt + (size_t)64 * K);
    __syncthreads();
    *(bf16x8*)(&As[sr][sc])      = a0;
    *(bf16x8*)(&As[sr + 64][sc]) = a1;
    *(bf16x8*)(&Bs[sr][sc])      = b0;
    *(bf16x8*)(&Bs[sr + 64][sc]) = b1;
    __syncthreads();
    bf16x8 af[4], bfr[4];
#pragma unroll
    for (int mt = 0; mt < 4; ++mt)
      af[mt] = *(const bf16x8*)(&As[wm + mt * 16 + l16][quad * 8]);
#pragma unroll
    for (int nt = 0; nt < 4; ++nt)
      bfr[nt] = *(const bf16x8*)(&Bs[wn + nt * 16 + l16][quad * 8]);
#pragma unroll
    for (int mt = 0; mt < 4; ++mt)
#pragma unroll
      for (int nt = 0; nt < 4; ++nt)
        acc[mt][nt] = __builtin_amdgcn_mfma_f32_16x16x32_bf16(af[mt], bfr[nt],
                                                              acc[mt][nt], 0, 0, 0);
  }
#pragma unroll
  for (int mt = 0; mt < 4; ++mt)
#pragma unroll
    for (int nt = 0; nt < 4; ++nt)
#pragma unroll
      for (int r = 0; r < 4; ++r) {
        int row = bm + wm + mt * 16 + quad * 4 + r;
        int col = bn + wn + nt * 16 + l16;
        size_t off = (size_t)row * N + col;
        float v = acc[mt][nt][r];
        if (cf32) ((float*)C)[off] = v;
        else      ((bf16*)C)[off] = (bf16)v;
      }
}

// ------------------------------------------------------------------
// RoPE (unchanged)
// ------------------------------------------------------------------
__global__ __launch_bounds__(256) void rope_kernel(bf16* __restrict__ qkv,
                                                   const int* __restrict__ pos) {
  int s = blockIdx.x;
  float p = (float)pos[s];
  bf16* row = qkv + (size_t)s * QKV_N;
  for (int i = threadIdx.x; i < 9 * 128; i += 256) {
    int h = i >> 7, d = i & 127;
    float inv = __expf(-(float)d * (9.210340371976184f / 128.0f));
    float th = p * inv;
    float sn, c;
    sincosf(th, &sn, &c);
    c  = (float)(bf16)c;
    sn = (float)(bf16)sn;
    bf16* x = row + ((h < 8) ? h * 256 : 2048);
    float x1 = (float)x[d], x2 = (float)x[d + 128];
    x[d]       = (bf16)(x1 * c - x2 * sn);
    x[d + 128] = (bf16)(x2 * c + x1 * sn);
  }
}

// ------------------------------------------------------------------
// Flash attention v4 = round-6 skeleton (4 waves x 16 q, kv-tile 64,
// proven swizzles: LDS rows are multiples of 128 B so bank group =
// chunk index; XOR over 8+ chunks => 2-way = free) + three changes:
//  1. register prefetch of next K/V tile (hides L2 latency in compute)
//  2. separate Ks/Vs buffers -> 2 barriers/iter instead of 4
//  3. balanced (head,qt) mapping: slot i and i+256 have qt summing to
//     63, so paired blocks on a CU do ~65 iters total (was 96/34 skew)
// ------------------------------------------------------------------
__global__ __launch_bounds__(256) void attn_kernel(const bf16* __restrict__ qkv,
                                                   const bf16* __restrict__ VT,
                                                   bf16* __restrict__ aout) {
  __shared__ __align__(16) bf16 Ks[64 * 256];     // 32 KB [kv64][d256]
  __shared__ __align__(16) bf16 Vs[256 * 64];     // 32 KB [d256][kv64]
  __shared__ __align__(16) bf16 Pl[4][16][72];    // per-wave P: C->A layout
  int tid  = threadIdx.x;
  int w = tid >> 6, lane = tid & 63;
  int quad = lane >> 4, l16 = lane & 15;
  int bx   = blockIdx.x;
  int p    = bx & 255;
  int qt, head;
  if (bx < 256) { qt = 63 - (p >> 2); head = p & 3; }       // heads 0-3, long first
  else          { qt = p >> 2;        head = 4 + (p & 3); } // heads 4-7, short first
  int qb   = qt * 64;
  int qw   = qb + w * 16;           // this wave's 16 q rows

  // Q fragments (A-layout), pre-scaled by 1/sqrt(256)
  const bf16* qrow = qkv + (size_t)(qw + l16) * QKV_N + head * D_HEAD + quad * 8;
  bf16x8 qf[8];
#pragma unroll
  for (int dc = 0; dc < 8; ++dc) {
    bf16x8 t = *(const bf16x8*)(qrow + dc * 32);
#pragma unroll
    for (int j = 0; j < 8; ++j) t[j] = (bf16)((float)t[j] * 0.0625f);
    qf[dc] = t;
  }

  f32x4 o[16] = {};
  float mrow[4] = {NEG_BIG, NEG_BIG, NEG_BIG, NEG_BIG};
  float lrow[4] = {0.f, 0.f, 0.f, 0.f};

  int kro = tid >> 5, kcc = tid & 31;   // K staging: rows c*8+kro, chunk kcc
  int vro = tid >> 3, vcc = tid & 7;    // V staging: rows c*32+vro, chunk vcc

  // ---- prefetch tile 0 into registers ----
  bf16x8 kreg[8], vreg[8];
#pragma unroll
  for (int c = 0; c < 8; ++c) {
    int r = c * 8 + kro;
    kreg[c] = *(const bf16x8*)(qkv + (size_t)r * QKV_N + 2048 + kcc * 8);
    int rv = c * 32 + vro;
    vreg[c] = *(const bf16x8*)(VT + (size_t)rv * S_LEN + vcc * 8);
  }

  int ntiles = qt + 1;
  for (int kt = 0; kt < ntiles; ++kt) {
    __syncthreads();                       // prior iter's Ks/Vs reads done
    // ---- commit prefetched tile to LDS ----
#pragma unroll
    for (int c = 0; c < 8; ++c) {
      int r = c * 8 + kro;
      *(bf16x8*)(Ks + r * 256 + ((kcc ^ (r & 31)) * 8)) = kreg[c];
      int rv = c * 32 + vro;
      *(bf16x8*)(Vs + rv * 64 + ((vcc ^ (rv & 7)) * 8)) = vreg[c];
    }
    __syncthreads();
    // ---- issue next tile's global loads (latency hidden by compute) ----
    int nf = (kt + 1 < ntiles) ? ((kt + 1) << 6) : qb;   // clamp: in-bounds, unused
#pragma unroll
    for (int c = 0; c < 8; ++c) {
      int r = c * 8 + kro;
      kreg[c] = *(const bf16x8*)(qkv + (size_t)(nf + r) * QKV_N + 2048 + kcc * 8);
      int rv = c * 32 + vro;
      vreg[c] = *(const bf16x8*)(VT + (size_t)rv * S_LEN + nf + vcc * 8);
    }
    // ---- S = Q K^T : 4 kv n-tiles x 8 d chunks ----
    int kv0 = kt << 6;
    f32x4 sv[4] = {};
#pragma unroll
    for (int dc = 0; dc < 8; ++dc)
#pragma unroll
      for (int n = 0; n < 4; ++n) {
        int row = n * 16 + l16;
        bf16x8 kf = *(const bf16x8*)(Ks + row * 256 + (((dc << 2) + quad) ^ (row & 31)) * 8);
        sv[n] = __builtin_amdgcn_mfma_f32_16x16x32_bf16(qf[dc], kf, sv[n], 0, 0, 0);
      }
    // ---- online softmax on 16x64 ----
    bool diag = (kt == qt);
    float pp[4][4];
    float mt[4] = {NEG_BIG, NEG_BIG, NEG_BIG, NEG_BIG};
#pragma unroll
    for (int n = 0; n < 4; ++n)
#pragma unroll
      for (int r = 0; r < 4; ++r) {
        float x = sv[n][r];
        if (diag && (n * 16 + l16 > w * 16 + quad * 4 + r)) x = NEG_BIG;
        pp[n][r] = x;
        mt[r] = fmaxf(mt[r], x);
      }
#pragma unroll
    for (int off = 8; off >= 1; off >>= 1)
#pragma unroll
      for (int r = 0; r < 4; ++r)
        mt[r] = fmaxf(mt[r], __shfl_xor(mt[r], off, 16));
    float alpha[4];
#pragma unroll
    for (int r = 0; r < 4; ++r) {
      float mnew = fmaxf(mrow[r], mt[r]);
      alpha[r] = __expf(mrow[r] - mnew);
      mrow[r] = mnew;
    }
    float rs[4] = {0.f, 0.f, 0.f, 0.f};
#pragma unroll
    for (int n = 0; n < 4; ++n)
#pragma unroll
      for (int r = 0; r < 4; ++r) {
        pp[n][r] = __expf(pp[n][r] - mrow[r]);
        rs[r] += pp[n][r];
      }
#pragma unroll
    for (int off = 8; off >= 1; off >>= 1)
#pragma unroll
      for (int r = 0; r < 4; ++r)
        rs[r] += __shfl_xor(rs[r], off, 16);
#pragma unroll
    for (int r = 0; r < 4; ++r) lrow[r] = lrow[r] * alpha[r] + rs[r];
#pragma unroll
    for (int dt = 0; dt < 16; ++dt)
#pragma unroll
      for (int r = 0; r < 4; ++r) o[dt][r] *= alpha[r];
    // ---- P (C/D layout) -> per-wave LDS -> A layout (wave-local) ----
#pragma unroll
    for (int n = 0; n < 4; ++n)
#pragma unroll
      for (int r = 0; r < 4; ++r)
        Pl[w][quad * 4 + r][n * 16 + l16] = (bf16)pp[n][r];
    asm volatile("s_waitcnt lgkmcnt(0)" ::: "memory");
    bf16x8 pa0 = *(const bf16x8*)(&Pl[w][l16][quad * 8]);
    bf16x8 pa1 = *(const bf16x8*)(&Pl[w][l16][32 + quad * 8]);
    // ---- O += P @ V ----
#pragma unroll
    for (int dt = 0; dt < 16; ++dt) {
      int row = dt * 16 + l16;
      const bf16* vb = Vs + row * 64;
      bf16x8 v0 = *(const bf16x8*)(vb + ((quad)     ^ (row & 7)) * 8);
      bf16x8 v1 = *(const bf16x8*)(vb + ((4 + quad) ^ (row & 7)) * 8);
      o[dt] = __builtin_amdgcn_mfma_f32_16x16x32_bf16(pa0, v0, o[dt], 0, 0, 0);
      o[dt] = __builtin_amdgcn_mfma_f32_16x16x32_bf16(pa1, v1, o[dt], 0, 0, 0);
    }
  }
  // ---- epilogue ----
  float invl[4];
#pragma unroll
  for (int r = 0; r < 4; ++r) invl[r] = 1.0f / lrow[r];
  bf16* orow = aout + (size_t)(qw + quad * 4) * HIDDEN + head * D_HEAD + l16;
#pragma unroll
  for (int dt = 0; dt < 16; ++dt)
#pragma unroll
    for (int r = 0; r < 4; ++r)
      orow[(size_t)r * HIDDEN + dt * 16] = (bf16)(o[dt][r] * invl[r]);
}

// ------------------------------------------------------------------
extern "C" void kernel_launch(void* const* d_in, const int* in_sizes, int n_in,
                              void* d_out, int out_size, void* d_ws, size_t ws_size,
                              hipStream_t stream) {
  if (ws_size < (size_t)WS_NEED) return;
  const void* hs  = d_in[0];
  const int*  pos = (const int*)d_in[1];
  const void* wq  = d_in[2];
  const void* wk  = d_in[3];
  const void* wv  = d_in[4];
  const void* wo  = d_in[5];

  char* ws = (char*)d_ws;
  bf16* wqkvT = (bf16*)(ws + OFF_WQKVT);   // [2560][2048]
  bf16* woT   = (bf16*)(ws + OFF_WOT);     // [2048][2048]
  bf16* qkv   = (bf16*)(ws + OFF_QKV);     // [4096][2560]
  bf16* VT    = (bf16*)(ws + OFF_VT);      // [256][4096]
  bf16* aout  = (bf16*)(ws + OFF_AOUT);    // [4096][2048]
  int*  flag  = (int*)(ws + OFF_FLAG);

  detect_dtype<<<1, 256, 0, stream>>>((const unsigned short*)wq, flag);
  build_wqkvT<<<dim3(QKV_N / 64, HIDDEN / 64), 256, 0, stream>>>(wq, wk, wv, wqkvT, flag);
  transpose_any<<<dim3(HIDDEN / 64, HIDDEN / 64), 256, 0, stream>>>(wo, 0, HIDDEN,
                                                                    woT, HIDDEN, flag);
  gemm128<<<dim3(QKV_N / 128, S_LEN / 128), 256, 0, stream>>>(hs, wqkvT, qkv,
                                                              S_LEN, QKV_N, HIDDEN,
                                                              flag, nullptr);
  rope_kernel<<<S_LEN, 256, 0, stream>>>(qkv, pos);
  transpose_any<<<dim3(D_HEAD / 64, S_LEN / 64), 256, 0, stream>>>(qkv, 2304, QKV_N,
                                                                   VT, S_LEN, nullptr);
  attn_kernel<<<N_HEADS * 64, 256, 0, stream>>>(qkv, VT, aout);
  gemm128<<<dim3(HIDDEN / 128, S_LEN / 128), 256, 0, stream>>>(aout, woT, d_out,
                                                               S_LEN, HIDDEN, HIDDEN,
                                                               nullptr, flag);
}